// Round 15
// baseline (534.873 us; speedup 1.0000x reference)
//
#include <hip/hip_runtime.h>
#include <hip/hip_bf16.h>
#include <math.h>

#define N_NODES 20000
#define N_EDGES 320000
#define DIN 50
#define HID 1024
#define NC3 726   // 6*121
#define NCLS 121
#define KCAT 2048
#define NQ 242    // [W3bar | S3bar] projected width

typedef __attribute__((ext_vector_type(8))) _Float16 half8;
typedef __attribute__((ext_vector_type(4))) float floatx4;

__device__ __forceinline__ unsigned short f2h(float v) {
    _Float16 h = (_Float16)v;
    return __builtin_bit_cast(unsigned short, h);
}
__device__ __forceinline__ float h2f(unsigned short u) {
    return (float)__builtin_bit_cast(_Float16, u);
}

// async global->LDS, 16B per lane. LDS dest must equal wave-uniform base + lane*16.
__device__ __forceinline__ void async16(const void* g, void* l) {
    __builtin_amdgcn_global_load_lds(
        (const __attribute__((address_space(1))) void*)g,
        (__attribute__((address_space(3))) void*)l,
        16, 0, 0);
}

// ---------------- CSR build ----------------

__global__ void zero_int_kernel(int* p, int n) {
    int i = blockIdx.x * blockDim.x + threadIdx.x;
    if (i < n) p[i] = 0;
}

// exclusive scan of deg -> offs/cursor; also emits dis = deg^-1/2
__global__ __launch_bounds__(1024) void scan_kernel(const int* __restrict__ deg,
                                                    int* __restrict__ offs,
                                                    int* __restrict__ cursor,
                                                    float* __restrict__ dis,
                                                    int n, int total) {
    __shared__ int part[1024];
    int t = threadIdx.x;
    const int CH = (n + 1023) / 1024;
    int base0 = t * CH;
    int s = 0;
    for (int i = 0; i < CH; ++i) {
        int idx = base0 + i;
        if (idx < n) s += deg[idx];
    }
    part[t] = s;
    __syncthreads();
    for (int d = 1; d < 1024; d <<= 1) {
        int v = (t >= d) ? part[t - d] : 0;
        __syncthreads();
        part[t] += v;
        __syncthreads();
    }
    int run = part[t] - s;
    for (int i = 0; i < CH; ++i) {
        int idx = base0 + i;
        if (idx < n) {
            int d = deg[idx];
            offs[idx] = run;
            cursor[idx] = run;
            dis[idx] = d > 0 ? rsqrtf((float)d) : 0.0f;
            run += d;
        }
    }
    if (t == 1023) offs[n] = total;
}

// scatter with inline norm = dis[row]*dis[col]
__global__ void scatter_kernel(const int* __restrict__ row, const int* __restrict__ col,
                               const float* __restrict__ dis, int* __restrict__ cursor,
                               int* __restrict__ csr_src, float* __restrict__ csr_w, int e) {
    int i = blockIdx.x * blockDim.x + threadIdx.x;
    if (i < e) {
        int r = row[i], c = col[i];
        float nm = dis[r] * dis[c];
        int pos = atomicAdd(&cursor[c], 1);
        csr_src[pos] = r;
        csr_w[pos] = nm;
    }
}

// ---------------- merged prep: count_deg + w1t + wt2 + wt3 + Qf zero ----
// blockIdx ranges: [0,2048) wt2 | [2048,2304) wt3 | [2304,2560) w1t |
//                  [2560,3810) count_deg | [3810, 3810+NZQ4) zero Qf (float4)
#define NQF (N_NODES * NQ)          // 4,840,000 floats
#define NQF4 (NQF / 4)              // 1,210,000 float4
#define NZQ4 ((NQF4 + 255) / 256)   // 4727 blocks

__global__ __launch_bounds__(256) void prep_kernel(const int* __restrict__ ecol,
                                                   int* __restrict__ deg,
                                                   const float* __restrict__ W1,
                                                   unsigned short* __restrict__ Bt1,
                                                   const float* __restrict__ W2,
                                                   const float* __restrict__ S2,
                                                   unsigned short* __restrict__ Bt2,
                                                   const float* __restrict__ W3,
                                                   const float* __restrict__ S3,
                                                   unsigned short* __restrict__ Bt3,
                                                   float* __restrict__ Qf) {
    __shared__ unsigned short tile[32][33];
    const int b = blockIdx.x;
    const int tid = threadIdx.x;

    if (b < 2048) {
        // W2/S2 [1024][1024] -> Bt2 fp16 [1024][2048] transposed via LDS 32x32 tiles
        int src = b >> 10;
        int t = b & 1023;
        int k0 = (t >> 5) * 32;
        int n0 = (t & 31) * 32;
        const float* W = src ? S2 : W2;
        int koff = src ? HID : 0;
        int tx = tid & 31;
        int ty = tid >> 5;
#pragma unroll
        for (int r = 0; r < 32; r += 8)
            tile[ty + r][tx] = f2h(W[(size_t)(k0 + ty + r) * HID + n0 + tx]);
        __syncthreads();
#pragma unroll
        for (int r = 0; r < 32; r += 8)
            Bt2[(size_t)(n0 + ty + r) * KCAT + koff + k0 + tx] = tile[tx][ty + r];
    } else if (b < 2304) {
        // W3/S3 [1024][726] -> head-mean + transpose -> Bt3 fp16 [242][1024]
        int tb = b - 2048;
        int src = tb >> 7;
        int t = tb & 127;
        int k0 = (t >> 2) * 32;
        int c0 = (t & 3) * 32;
        const float* W = src ? S3 : W3;
        int tx = tid & 31;
        int ty = tid >> 5;
#pragma unroll
        for (int r = 0; r < 32; r += 8) {
            int k = k0 + ty + r, c = c0 + tx;
            float v = 0.0f;
            if (c < NCLS) {
                const float* p = W + (size_t)k * NC3 + c;
                v = (p[0] + p[121] + p[242] + p[363] + p[484] + p[605]) * (1.0f / 6.0f);
            }
            tile[ty + r][tx] = f2h(v);
        }
        __syncthreads();
#pragma unroll
        for (int r = 0; r < 32; r += 8) {
            int c = c0 + ty + r;
            if (c < NCLS)
                Bt3[(size_t)(src * NCLS + c) * HID + k0 + tx] = tile[tx][ty + r];
        }
    } else if (b < 2560) {
        // W1 [50][1024] -> Bt1 fp16 [1024][64] transposed, padded
        int i = (b - 2304) * 256 + tid;
        int n = i / 64, k = i - n * 64;
        Bt1[i] = (k < DIN) ? f2h(W1[(size_t)k * HID + n]) : (unsigned short)0;
    } else if (b < 3810) {
        // degree count
        int i = (b - 2560) * 256 + tid;
        if (i < N_EDGES) atomicAdd(&deg[ecol[i]], 1);
    } else {
        // zero Qf (fp32 split-K accumulator), float4
        int i4 = (b - 3810) * 256 + tid;
        if (i4 < NQF4) ((float4*)Qf)[i4] = (float4){0.f, 0.f, 0.f, 0.f};
    }
}

// ---------------- aggregations ----------------

// gX = A . X  (50-wide fp32 gather -> fp16 out, rows padded to 64)
__global__ __launch_bounds__(64) void aggX_kernel(const float* __restrict__ X,
                                                  const int* __restrict__ offs,
                                                  const int* __restrict__ csr_src,
                                                  const float* __restrict__ csr_w,
                                                  unsigned short* __restrict__ gX) {
    int n = blockIdx.x;
    int t = threadIdx.x;
    float a = 0.0f;
    if (t < DIN) {
        int p0 = offs[n], p1 = offs[n + 1];
        for (int p = p0; p < p1; ++p) {
            a = fmaf(csr_w[p], X[(size_t)csr_src[p] * DIN + t], a);
        }
    }
    gX[(size_t)n * 64 + t] = (t < DIN) ? f2h(a) : (unsigned short)0;
}

// g = A . h, 16 slices x 64 cols, two dispatch phases, XCD-pinned:
// f&7 -> XCD; s_outer=(f>>3)/625 in {0,1}; slice = s_outer*8 + xcd.
// Per-XCD live gather set = 20000 x 64 x 2B = 2.56 MB < 4 MiB L2.
// Block = 32 nodes x 8 col-threads, 16 B per edge per thread.
__global__ __launch_bounds__(256) void agg_slice_kernel(const unsigned short* __restrict__ h,
                                                        const int* __restrict__ offs,
                                                        const int* __restrict__ csr_src,
                                                        const float* __restrict__ csr_w,
                                                        unsigned short* __restrict__ g) {
    const int f = blockIdx.x;
    const int xcd = f & 7;
    const int r0 = f >> 3;          // 0..1249
    const int s_outer = r0 / 625;   // phase 0 or 1
    const int nb = r0 % 625;
    const int slice = s_outer * 8 + xcd;
    const int tid = threadIdx.x;
    const int n = nb * 32 + (tid >> 3);
    const int coloff = slice * 64 + (tid & 7) * 8;
    const unsigned short* hp = h + coloff;

    float a[8] = {0, 0, 0, 0, 0, 0, 0, 0};
    int p0 = offs[n], p1 = offs[n + 1];
    for (int p = p0; p < p1; ++p) {
        int s = csr_src[p];
        float w = csr_w[p];
        uint4 v = *(const uint4*)&hp[(size_t)s * HID];
        const unsigned short* vs = (const unsigned short*)&v;
#pragma unroll
        for (int j = 0; j < 8; ++j) a[j] = fmaf(w, h2f(vs[j]), a[j]);
    }
    unsigned short ov[8];
#pragma unroll
    for (int j = 0; j < 8; ++j) ov[j] = f2h(a[j]);
    *(uint4*)&g[(size_t)n * HID + coloff] = *(const uint4*)ov;
}

// layer-3 final: out[n][c] = sum_p w_p * Qf[src_p][c] + Qf[n][121+c]  (Qf fp32)
__global__ __launch_bounds__(256) void agg3_kernel(const float* __restrict__ Qf,
                                                   const int* __restrict__ offs,
                                                   const int* __restrict__ csr_src,
                                                   const float* __restrict__ csr_w,
                                                   float* __restrict__ out) {
    int n = blockIdx.x * 2 + (threadIdx.x >> 7);
    int c = threadIdx.x & 127;
    if (c >= NCLS) return;
    float a = 0.0f;
    int p0 = offs[n], p1 = offs[n + 1];
    for (int p = p0; p < p1; ++p) {
        a = fmaf(csr_w[p], Qf[(size_t)csr_src[p] * NQ + c], a);
    }
    a += Qf[(size_t)n * NQ + NCLS + c];
    out[(size_t)n * NCLS + c] = a;
}

// ---------------- fp16 MFMA GEMM: dbuf async pipeline + XOR-swizzled LDS + XCD grouping ----
// K-loop and round-12 block order (measured best: 130 us / MfmaUtil 28% / 0 conflicts).
// EPI 0: elu -> fp16 Co. EPI 1: fp32 atomicAdd (split-K). EPI 2: plain fp16 Co.

#define GBM 128
#define GBN 128
#define GBK 32

template <int EPI>
__global__ __launch_bounds__(256, 4) void mfma_gemm_kernel(
        const unsigned short* __restrict__ Ag, const unsigned short* __restrict__ Ah,
        const unsigned short* __restrict__ Bt,
        void* __restrict__ Co,
        int M, int N, int ldc, int ktot, int khalf, int kw,
        int NB, int MB, int mchunk) {
    __shared__ __align__(16) unsigned short sA[2][GBM * GBK];
    __shared__ __align__(16) unsigned short sB[2][GBN * GBK];

    // --- XCD-grouped block swizzle (round-12 order) ---
    const int f = blockIdx.x;
    const int xcd = f & 7;
    const int r0 = f >> 3;
    const int nB = r0 % NB;
    const int mi = r0 / NB;
    const int mB = xcd * mchunk + mi;
    if (mB >= MB) return;
    const int bm = mB * GBM;
    const int bn = nB * GBN;
    const int ks = blockIdx.y;

    const int tid = threadIdx.x;
    const int lane = tid & 63;
    const int wave = tid >> 6;
    const int wm = wave >> 1;
    const int wn = wave & 1;

    // staging map: thread t covers row (t>>2)+64p; stored chunk slot t&3;
    // global chunk = (t&3) ^ ((row>>1)&3).
    const int st_r = tid >> 2;
    const int st_slot = tid & 3;
    const int st_c = (st_slot ^ ((st_r >> 1) & 3)) * 8;
    const int st_lds = st_r * GBK + st_slot * 8;

    int agm[2], bgn[2];
#pragma unroll
    for (int p = 0; p < 2; ++p) {
        int gm = bm + st_r + p * 64;
        agm[p] = gm < M ? gm : M - 1;
        int gn = bn + st_r + p * 64;
        bgn[p] = gn < N ? gn : N - 1;
    }

    const int frow = lane & 15;
    const int fkc = (((lane >> 4) ^ ((frow >> 1) & 3))) * 8;

    floatx4 acc[4][4];
#pragma unroll
    for (int i = 0; i < 4; ++i)
#pragma unroll
        for (int j = 0; j < 4; ++j) acc[i][j] = (floatx4){0.f, 0.f, 0.f, 0.f};

    auto issue = [&](int k0, int buf) {
        const unsigned short* ap = (k0 < khalf) ? Ag : Ah;
        int ka = (k0 < khalf) ? k0 : k0 - khalf;
#pragma unroll
        for (int p = 0; p < 2; ++p) {
            async16(&ap[(size_t)agm[p] * khalf + ka + st_c],
                    &sA[buf][p * 64 * GBK + st_lds]);
            async16(&Bt[(size_t)bgn[p] * ktot + k0 + st_c],
                    &sB[buf][p * 64 * GBK + st_lds]);
        }
    };

    const int tw = kw / GBK;
    const int t0 = ks * tw;       // even for all our launches -> buf parity (t&1) ok
    const int t1 = t0 + tw;

    issue(t0 * GBK, 0);

    for (int t = t0; t < t1; ++t) {
        __syncthreads();  // drains DMA for tile t (issued one compute-phase ago)
        if (t + 1 < t1) issue((t + 1) * GBK, (t + 1) & 1);

        const unsigned short* a_base = sA[t & 1];
        const unsigned short* b_base = sB[t & 1];
        half8 fa[4], fb[4];
#pragma unroll
        for (int i = 0; i < 4; ++i)
            fa[i] = *(const half8*)&a_base[(wm * 64 + i * 16 + frow) * GBK + fkc];
#pragma unroll
        for (int j = 0; j < 4; ++j)
            fb[j] = *(const half8*)&b_base[(wn * 64 + j * 16 + frow) * GBK + fkc];
#pragma unroll
        for (int i = 0; i < 4; ++i)
#pragma unroll
            for (int j = 0; j < 4; ++j)
                acc[i][j] = __builtin_amdgcn_mfma_f32_16x16x32_f16(fa[i], fb[j], acc[i][j], 0, 0, 0);
    }

    // C/D layout: col=lane&15, row=(lane>>4)*4+reg
    const int c_r0 = (lane >> 4) * 4;
    const int c_c = lane & 15;
#pragma unroll
    for (int i = 0; i < 4; ++i)
#pragma unroll
        for (int j = 0; j < 4; ++j) {
            int gn = bn + wn * 64 + j * 16 + c_c;
            if (gn >= N) continue;
#pragma unroll
            for (int r = 0; r < 4; ++r) {
                int gm = bm + wm * 64 + i * 16 + c_r0 + r;
                if (gm >= M) continue;
                float v = acc[i][j][r];
                if (EPI == 0) {
                    v = v > 0 ? v : expf(v) - 1.0f;  // elu
                    ((unsigned short*)Co)[(size_t)gm * ldc + gn] = f2h(v);
                } else if (EPI == 1) {
                    atomicAdd(&((float*)Co)[(size_t)gm * ldc + gn], v);
                } else {
                    ((unsigned short*)Co)[(size_t)gm * ldc + gn] = f2h(v);
                }
            }
        }
}

// ---------------- launch ----------------

static inline size_t align_up(size_t x, size_t a) { return (x + a - 1) & ~(a - 1); }

extern "C" void kernel_launch(void* const* d_in, const int* in_sizes, int n_in,
                              void* d_out, int out_size, void* d_ws, size_t ws_size,
                              hipStream_t stream) {
    const float* X  = (const float*)d_in[0];
    const int* erow = (const int*)d_in[1];
    const int* ecol = (const int*)d_in[1] + N_EDGES;
    const float* W1 = (const float*)d_in[2];
    const float* W2 = (const float*)d_in[3];
    const float* S2 = (const float*)d_in[4];
    const float* W3 = (const float*)d_in[5];
    const float* S3 = (const float*)d_in[6];
    float* out = (float*)d_out;

    // workspace carve-up
    char* w = (char*)d_ws;
    int* deg     = (int*)w;             w += align_up((size_t)N_NODES * 4, 256);
    int* offs    = (int*)w;             w += align_up((size_t)(N_NODES + 1) * 4, 256);
    int* cursor  = (int*)w;             w += align_up((size_t)N_NODES * 4, 256);
    int* csr_src = (int*)w;             w += align_up((size_t)N_EDGES * 4, 256);
    float* dis   = (float*)w;           w += align_up((size_t)N_NODES * 4, 256);
    float* csr_w = (float*)w;           w += align_up((size_t)N_EDGES * 4, 256);
    float* Qf    = (float*)w;           w += align_up((size_t)NQF * 4, 256);
    unsigned short* gXh = (unsigned short*)w; w += align_up((size_t)N_NODES * 64 * 2, 256);
    unsigned short* h1 = (unsigned short*)w;  w += align_up((size_t)N_NODES * HID * 2, 256);
    unsigned short* g  = (unsigned short*)w;  w += align_up((size_t)N_NODES * HID * 2, 256);
    unsigned short* h2 = (unsigned short*)w;  w += align_up((size_t)N_NODES * HID * 2, 256);
    unsigned short* Bt1 = (unsigned short*)w; w += align_up((size_t)HID * 64 * 2, 256);
    unsigned short* Bt2 = (unsigned short*)w; w += align_up((size_t)HID * KCAT * 2, 256);
    unsigned short* Bt3 = (unsigned short*)w; w += align_up((size_t)NQ * HID * 2, 256);

    const int TB = 256;
    int nb_n = (N_NODES + TB - 1) / TB;

    // 1. zero deg; 2. merged prep (count_deg + weight prep + Qf zero)
    zero_int_kernel<<<nb_n, TB, 0, stream>>>(deg, N_NODES);
    prep_kernel<<<3810 + NZQ4, 256, 0, stream>>>(ecol, deg, W1, Bt1, W2, S2, Bt2,
                                                 W3, S3, Bt3, Qf);

    // 3. scan; 4. scatter
    scan_kernel<<<1, 1024, 0, stream>>>(deg, offs, cursor, dis, N_NODES, N_EDGES);
    scatter_kernel<<<(N_EDGES + TB - 1) / TB, TB, 0, stream>>>(erow, ecol, dis, cursor,
                                                               csr_src, csr_w, N_EDGES);

    const int MB = (N_NODES + GBM - 1) / GBM;   // 157
    const int mchunk = (MB + 7) / 8;            // 20
    const int NB2 = HID / GBN;                  // 8
    const int NB3 = (NQ + GBN - 1) / GBN;       // 2
    const int AGG_GRID = 8 * 1250;              // 16 slices x 625 node-blocks, 2 phases

    // 5-6. layer 1: gX = A.X ; h1 = elu(gX @ W1)
    aggX_kernel<<<N_NODES, 64, 0, stream>>>(X, offs, csr_src, csr_w, gXh);
    mfma_gemm_kernel<0><<<dim3(8 * mchunk * NB2, 1), 256, 0, stream>>>(
        gXh, gXh, Bt1, h1, N_NODES, HID, HID, 64, 64, 64, NB2, MB, mchunk);

    // 7-8. layer 2: g1 = A.h1 ; h2 = elu([g1|h1] @ [W2;S2])
    agg_slice_kernel<<<AGG_GRID, 256, 0, stream>>>(h1, offs, csr_src, csr_w, g);
    mfma_gemm_kernel<0><<<dim3(8 * mchunk * NB2, 1), 256, 0, stream>>>(
        g, h1, Bt2, h2, N_NODES, HID, HID, KCAT, HID, KCAT, NB2, MB, mchunk);

    // 9-10. layer 3 (project-then-aggregate, split-K=2):
    //        Qf += h2 @ [W3bar|S3bar]  (A = h2 directly — round-14 bug was A = agg(h2));
    //        out = agg(Qf_w) + Qf_s
    mfma_gemm_kernel<1><<<dim3(8 * mchunk * NB3, 2), 256, 0, stream>>>(
        h2, h2, Bt3, Qf, N_NODES, NQ, NQ, HID, HID, HID / 2, NB3, MB, mchunk);
    agg3_kernel<<<N_NODES / 2, 256, 0, stream>>>(Qf, offs, csr_src, csr_w, out);
}

// Round 16
// 485.721 us; speedup vs baseline: 1.1012x; 1.1012x over previous
//
#include <hip/hip_runtime.h>
#include <hip/hip_bf16.h>
#include <math.h>

#define N_NODES 20000
#define N_EDGES 320000
#define DIN 50
#define HID 1024
#define NC3 726   // 6*121
#define NCLS 121
#define KCAT 2048
#define NQ 242    // [W3bar | S3bar] projected width

typedef __attribute__((ext_vector_type(8))) _Float16 half8;
typedef __attribute__((ext_vector_type(4))) float floatx4;

__device__ __forceinline__ unsigned short f2h(float v) {
    _Float16 h = (_Float16)v;
    return __builtin_bit_cast(unsigned short, h);
}
__device__ __forceinline__ float h2f(unsigned short u) {
    return (float)__builtin_bit_cast(_Float16, u);
}

// async global->LDS, 16B per lane. LDS dest must equal wave-uniform base + lane*16.
__device__ __forceinline__ void async16(const void* g, void* l) {
    __builtin_amdgcn_global_load_lds(
        (const __attribute__((address_space(1))) void*)g,
        (__attribute__((address_space(3))) void*)l,
        16, 0, 0);
}

// ---------------- CSR build ----------------

__global__ void zero_int_kernel(int* p, int n) {
    int i = blockIdx.x * blockDim.x + threadIdx.x;
    if (i < n) p[i] = 0;
}

// exclusive scan of deg -> offs/cursor; also emits dis = deg^-1/2
__global__ __launch_bounds__(1024) void scan_kernel(const int* __restrict__ deg,
                                                    int* __restrict__ offs,
                                                    int* __restrict__ cursor,
                                                    float* __restrict__ dis,
                                                    int n, int total) {
    __shared__ int part[1024];
    int t = threadIdx.x;
    const int CH = (n + 1023) / 1024;
    int base0 = t * CH;
    int s = 0;
    for (int i = 0; i < CH; ++i) {
        int idx = base0 + i;
        if (idx < n) s += deg[idx];
    }
    part[t] = s;
    __syncthreads();
    for (int d = 1; d < 1024; d <<= 1) {
        int v = (t >= d) ? part[t - d] : 0;
        __syncthreads();
        part[t] += v;
        __syncthreads();
    }
    int run = part[t] - s;
    for (int i = 0; i < CH; ++i) {
        int idx = base0 + i;
        if (idx < n) {
            int d = deg[idx];
            offs[idx] = run;
            cursor[idx] = run;
            dis[idx] = d > 0 ? rsqrtf((float)d) : 0.0f;
            run += d;
        }
    }
    if (t == 1023) offs[n] = total;
}

// scatter with inline norm = dis[row]*dis[col]
__global__ void scatter_kernel(const int* __restrict__ row, const int* __restrict__ col,
                               const float* __restrict__ dis, int* __restrict__ cursor,
                               int* __restrict__ csr_src, float* __restrict__ csr_w, int e) {
    int i = blockIdx.x * blockDim.x + threadIdx.x;
    if (i < e) {
        int r = row[i], c = col[i];
        float nm = dis[r] * dis[c];
        int pos = atomicAdd(&cursor[c], 1);
        csr_src[pos] = r;
        csr_w[pos] = nm;
    }
}

// ---------------- merged prep: count_deg + w1t + wt2 transpose + wt3 fold+transpose ----
// blockIdx ranges:  [0,2048) wt2 | [2048,2304) wt3 | [2304,2560) w1t | [2560,3810) count_deg
__global__ __launch_bounds__(256) void prep_kernel(const int* __restrict__ ecol,
                                                   int* __restrict__ deg,
                                                   const float* __restrict__ W1,
                                                   unsigned short* __restrict__ Bt1,
                                                   const float* __restrict__ W2,
                                                   const float* __restrict__ S2,
                                                   unsigned short* __restrict__ Bt2,
                                                   const float* __restrict__ W3,
                                                   const float* __restrict__ S3,
                                                   unsigned short* __restrict__ Bt3) {
    __shared__ unsigned short tile[32][33];
    const int b = blockIdx.x;
    const int tid = threadIdx.x;

    if (b < 2048) {
        // W2/S2 [1024][1024] -> Bt2 fp16 [1024][2048] transposed via LDS 32x32 tiles
        int src = b >> 10;
        int t = b & 1023;
        int k0 = (t >> 5) * 32;
        int n0 = (t & 31) * 32;
        const float* W = src ? S2 : W2;
        int koff = src ? HID : 0;
        int tx = tid & 31;
        int ty = tid >> 5;
#pragma unroll
        for (int r = 0; r < 32; r += 8)
            tile[ty + r][tx] = f2h(W[(size_t)(k0 + ty + r) * HID + n0 + tx]);
        __syncthreads();
#pragma unroll
        for (int r = 0; r < 32; r += 8)
            Bt2[(size_t)(n0 + ty + r) * KCAT + koff + k0 + tx] = tile[tx][ty + r];
    } else if (b < 2304) {
        // W3/S3 [1024][726] -> head-mean + transpose -> Bt3 fp16 [242][1024]
        int tb = b - 2048;
        int src = tb >> 7;
        int t = tb & 127;
        int k0 = (t >> 2) * 32;
        int c0 = (t & 3) * 32;
        const float* W = src ? S3 : W3;
        int tx = tid & 31;
        int ty = tid >> 5;
#pragma unroll
        for (int r = 0; r < 32; r += 8) {
            int k = k0 + ty + r, c = c0 + tx;
            float v = 0.0f;
            if (c < NCLS) {
                const float* p = W + (size_t)k * NC3 + c;
                v = (p[0] + p[121] + p[242] + p[363] + p[484] + p[605]) * (1.0f / 6.0f);
            }
            tile[ty + r][tx] = f2h(v);
        }
        __syncthreads();
#pragma unroll
        for (int r = 0; r < 32; r += 8) {
            int c = c0 + ty + r;
            if (c < NCLS)
                Bt3[(size_t)(src * NCLS + c) * HID + k0 + tx] = tile[tx][ty + r];
        }
    } else if (b < 2560) {
        // W1 [50][1024] -> Bt1 fp16 [1024][64] transposed, padded
        int i = (b - 2304) * 256 + tid;
        int n = i / 64, k = i - n * 64;
        Bt1[i] = (k < DIN) ? f2h(W1[(size_t)k * HID + n]) : (unsigned short)0;
    } else {
        // degree count
        int i = (b - 2560) * 256 + tid;
        if (i < N_EDGES) atomicAdd(&deg[ecol[i]], 1);
    }
}

// ---------------- aggregations ----------------

// gX = A . X  (50-wide fp32 gather -> fp16 out, rows padded to 64)
__global__ __launch_bounds__(64) void aggX_kernel(const float* __restrict__ X,
                                                  const int* __restrict__ offs,
                                                  const int* __restrict__ csr_src,
                                                  const float* __restrict__ csr_w,
                                                  unsigned short* __restrict__ gX) {
    int n = blockIdx.x;
    int t = threadIdx.x;
    float a = 0.0f;
    if (t < DIN) {
        int p0 = offs[n], p1 = offs[n + 1];
        for (int p = p0; p < p1; ++p) {
            a = fmaf(csr_w[p], X[(size_t)csr_src[p] * DIN + t], a);
        }
    }
    gX[(size_t)n * 64 + t] = (t < DIN) ? f2h(a) : (unsigned short)0;
}

// g = A . h, 8 slices x 128 cols, XCD-pinned (measured-best agg variant; further
// slicing refinements were neutral/negative in rounds 10/14/15 — latency/L3-floor)
__global__ __launch_bounds__(256) void agg_slice_kernel(const unsigned short* __restrict__ h,
                                                        const int* __restrict__ offs,
                                                        const int* __restrict__ csr_src,
                                                        const float* __restrict__ csr_w,
                                                        unsigned short* __restrict__ g) {
    const int f = blockIdx.x;
    const int slice = f & 7;
    const int nb = f >> 3;
    const int tid = threadIdx.x;
    const int n = nb * 16 + (tid >> 4);
    const int coloff = slice * 128 + (tid & 15) * 8;
    const unsigned short* hp = h + coloff;

    float a[8] = {0, 0, 0, 0, 0, 0, 0, 0};
    int p0 = offs[n], p1 = offs[n + 1];
    for (int p = p0; p < p1; ++p) {
        int s = csr_src[p];
        float w = csr_w[p];
        uint4 v = *(const uint4*)&hp[(size_t)s * HID];
        const unsigned short* vs = (const unsigned short*)&v;
#pragma unroll
        for (int j = 0; j < 8; ++j) a[j] = fmaf(w, h2f(vs[j]), a[j]);
    }
    unsigned short ov[8];
#pragma unroll
    for (int j = 0; j < 8; ++j) ov[j] = f2h(a[j]);
    *(uint4*)&g[(size_t)n * HID + coloff] = *(const uint4*)ov;
}

// layer-3 final: out[n][c] = sum_p w_p * Q[src_p][c] + Q[n][121+c]  (Q fp16 [N][242])
__global__ __launch_bounds__(256) void agg3_kernel(const unsigned short* __restrict__ Q,
                                                   const int* __restrict__ offs,
                                                   const int* __restrict__ csr_src,
                                                   const float* __restrict__ csr_w,
                                                   float* __restrict__ out) {
    int n = blockIdx.x * 2 + (threadIdx.x >> 7);
    int c = threadIdx.x & 127;
    if (c >= NCLS) return;
    float a = 0.0f;
    int p0 = offs[n], p1 = offs[n + 1];
    for (int p = p0; p < p1; ++p) {
        a = fmaf(csr_w[p], h2f(Q[(size_t)csr_src[p] * NQ + c]), a);
    }
    a += h2f(Q[(size_t)n * NQ + NCLS + c]);
    out[(size_t)n * NCLS + c] = a;
}

// ---------------- fp16 MFMA GEMM: dbuf async pipeline + XOR-swizzled LDS + XCD grouping ----
// Round-12 block order (measured best: 130 us / MfmaUtil 28% / FETCH 72.9 MB / 0 conflicts).
// EPI 0: elu -> fp16 Co. EPI 1: fp32 atomicAdd (unused here). EPI 2: plain fp16 Co.

#define GBM 128
#define GBN 128
#define GBK 32

template <int EPI>
__global__ __launch_bounds__(256, 4) void mfma_gemm_kernel(
        const unsigned short* __restrict__ Ag, const unsigned short* __restrict__ Ah,
        const unsigned short* __restrict__ Bt,
        void* __restrict__ Co,
        int M, int N, int ldc, int ktot, int khalf, int kw,
        int NB, int MB, int mchunk) {
    __shared__ __align__(16) unsigned short sA[2][GBM * GBK];
    __shared__ __align__(16) unsigned short sB[2][GBN * GBK];

    // --- XCD-grouped block swizzle (round-12 order) ---
    const int f = blockIdx.x;
    const int xcd = f & 7;
    const int r0 = f >> 3;
    const int nB = r0 % NB;
    const int mi = r0 / NB;
    const int mB = xcd * mchunk + mi;
    if (mB >= MB) return;
    const int bm = mB * GBM;
    const int bn = nB * GBN;
    const int ks = blockIdx.y;

    const int tid = threadIdx.x;
    const int lane = tid & 63;
    const int wave = tid >> 6;
    const int wm = wave >> 1;
    const int wn = wave & 1;

    // staging map: thread t covers row (t>>2)+64p; stored chunk slot t&3;
    // global chunk = (t&3) ^ ((row>>1)&3).
    const int st_r = tid >> 2;
    const int st_slot = tid & 3;
    const int st_c = (st_slot ^ ((st_r >> 1) & 3)) * 8;
    const int st_lds = st_r * GBK + st_slot * 8;

    int agm[2], bgn[2];
#pragma unroll
    for (int p = 0; p < 2; ++p) {
        int gm = bm + st_r + p * 64;
        agm[p] = gm < M ? gm : M - 1;
        int gn = bn + st_r + p * 64;
        bgn[p] = gn < N ? gn : N - 1;
    }

    const int frow = lane & 15;
    const int fkc = (((lane >> 4) ^ ((frow >> 1) & 3))) * 8;

    floatx4 acc[4][4];
#pragma unroll
    for (int i = 0; i < 4; ++i)
#pragma unroll
        for (int j = 0; j < 4; ++j) acc[i][j] = (floatx4){0.f, 0.f, 0.f, 0.f};

    auto issue = [&](int k0, int buf) {
        const unsigned short* ap = (k0 < khalf) ? Ag : Ah;
        int ka = (k0 < khalf) ? k0 : k0 - khalf;
#pragma unroll
        for (int p = 0; p < 2; ++p) {
            async16(&ap[(size_t)agm[p] * khalf + ka + st_c],
                    &sA[buf][p * 64 * GBK + st_lds]);
            async16(&Bt[(size_t)bgn[p] * ktot + k0 + st_c],
                    &sB[buf][p * 64 * GBK + st_lds]);
        }
    };

    const int tw = kw / GBK;
    const int t0 = ks * tw;
    const int t1 = t0 + tw;

    issue(t0 * GBK, 0);

    for (int t = t0; t < t1; ++t) {
        __syncthreads();  // drains DMA for tile t (issued one compute-phase ago)
        if (t + 1 < t1) issue((t + 1) * GBK, (t + 1) & 1);

        const unsigned short* a_base = sA[t & 1];
        const unsigned short* b_base = sB[t & 1];
        half8 fa[4], fb[4];
#pragma unroll
        for (int i = 0; i < 4; ++i)
            fa[i] = *(const half8*)&a_base[(wm * 64 + i * 16 + frow) * GBK + fkc];
#pragma unroll
        for (int j = 0; j < 4; ++j)
            fb[j] = *(const half8*)&b_base[(wn * 64 + j * 16 + frow) * GBK + fkc];
#pragma unroll
        for (int i = 0; i < 4; ++i)
#pragma unroll
            for (int j = 0; j < 4; ++j)
                acc[i][j] = __builtin_amdgcn_mfma_f32_16x16x32_f16(fa[i], fb[j], acc[i][j], 0, 0, 0);
    }

    // C/D layout: col=lane&15, row=(lane>>4)*4+reg
    const int c_r0 = (lane >> 4) * 4;
    const int c_c = lane & 15;
#pragma unroll
    for (int i = 0; i < 4; ++i)
#pragma unroll
        for (int j = 0; j < 4; ++j) {
            int gn = bn + wn * 64 + j * 16 + c_c;
            if (gn >= N) continue;
#pragma unroll
            for (int r = 0; r < 4; ++r) {
                int gm = bm + wm * 64 + i * 16 + c_r0 + r;
                if (gm >= M) continue;
                float v = acc[i][j][r];
                if (EPI == 0) {
                    v = v > 0 ? v : expf(v) - 1.0f;  // elu
                    ((unsigned short*)Co)[(size_t)gm * ldc + gn] = f2h(v);
                } else if (EPI == 1) {
                    atomicAdd(&((float*)Co)[(size_t)gm * ldc + gn], v);
                } else {
                    ((unsigned short*)Co)[(size_t)gm * ldc + gn] = f2h(v);
                }
            }
        }
}

// ---------------- launch ----------------

static inline size_t align_up(size_t x, size_t a) { return (x + a - 1) & ~(a - 1); }

extern "C" void kernel_launch(void* const* d_in, const int* in_sizes, int n_in,
                              void* d_out, int out_size, void* d_ws, size_t ws_size,
                              hipStream_t stream) {
    const float* X  = (const float*)d_in[0];
    const int* erow = (const int*)d_in[1];
    const int* ecol = (const int*)d_in[1] + N_EDGES;
    const float* W1 = (const float*)d_in[2];
    const float* W2 = (const float*)d_in[3];
    const float* S2 = (const float*)d_in[4];
    const float* W3 = (const float*)d_in[5];
    const float* S3 = (const float*)d_in[6];
    float* out = (float*)d_out;

    // workspace carve-up
    char* w = (char*)d_ws;
    int* deg     = (int*)w;             w += align_up((size_t)N_NODES * 4, 256);
    int* offs    = (int*)w;             w += align_up((size_t)(N_NODES + 1) * 4, 256);
    int* cursor  = (int*)w;             w += align_up((size_t)N_NODES * 4, 256);
    int* csr_src = (int*)w;             w += align_up((size_t)N_EDGES * 4, 256);
    float* dis   = (float*)w;           w += align_up((size_t)N_NODES * 4, 256);
    float* csr_w = (float*)w;           w += align_up((size_t)N_EDGES * 4, 256);
    unsigned short* gXh = (unsigned short*)w; w += align_up((size_t)N_NODES * 64 * 2, 256);
    unsigned short* h1 = (unsigned short*)w;  w += align_up((size_t)N_NODES * HID * 2, 256);
    unsigned short* g  = (unsigned short*)w;  w += align_up((size_t)N_NODES * HID * 2, 256);
    unsigned short* h2 = (unsigned short*)w;  w += align_up((size_t)N_NODES * HID * 2, 256);
    unsigned short* Qh = (unsigned short*)w;  w += align_up((size_t)N_NODES * NQ * 2, 256);
    unsigned short* Bt1 = (unsigned short*)w; w += align_up((size_t)HID * 64 * 2, 256);
    unsigned short* Bt2 = (unsigned short*)w; w += align_up((size_t)HID * KCAT * 2, 256);
    unsigned short* Bt3 = (unsigned short*)w; w += align_up((size_t)NQ * HID * 2, 256);

    const int TB = 256;
    int nb_n = (N_NODES + TB - 1) / TB;

    // 1. zero deg; 2. merged prep (count_deg + all weight prep)
    zero_int_kernel<<<nb_n, TB, 0, stream>>>(deg, N_NODES);
    prep_kernel<<<3810, 256, 0, stream>>>(ecol, deg, W1, Bt1, W2, S2, Bt2, W3, S3, Bt3);

    // 3. scan; 4. scatter
    scan_kernel<<<1, 1024, 0, stream>>>(deg, offs, cursor, dis, N_NODES, N_EDGES);
    scatter_kernel<<<(N_EDGES + TB - 1) / TB, TB, 0, stream>>>(erow, ecol, dis, cursor,
                                                               csr_src, csr_w, N_EDGES);

    const int MB = (N_NODES + GBM - 1) / GBM;   // 157
    const int mchunk = (MB + 7) / 8;            // 20
    const int NB2 = HID / GBN;                  // 8
    const int NB3 = (NQ + GBN - 1) / GBN;       // 2
    const int AGG_GRID = 8 * (N_NODES / 16);    // 8 slices x 1250 node-blocks

    // 5-6. layer 1: gX = A.X ; h1 = elu(gX @ W1)
    aggX_kernel<<<N_NODES, 64, 0, stream>>>(X, offs, csr_src, csr_w, gXh);
    mfma_gemm_kernel<0><<<dim3(8 * mchunk * NB2, 1), 256, 0, stream>>>(
        gXh, gXh, Bt1, h1, N_NODES, HID, HID, 64, 64, 64, NB2, MB, mchunk);

    // 7-8. layer 2: g1 = A.h1 ; h2 = elu([g1|h1] @ [W2;S2])
    agg_slice_kernel<<<AGG_GRID, 256, 0, stream>>>(h1, offs, csr_src, csr_w, g);
    mfma_gemm_kernel<0><<<dim3(8 * mchunk * NB2, 1), 256, 0, stream>>>(
        g, h1, Bt2, h2, N_NODES, HID, HID, KCAT, HID, KCAT, NB2, MB, mchunk);

    // 9-10. layer 3 (project-then-aggregate): Q = h2 @ [W3bar|S3bar] (fp16);
    //        out = agg(Q_w) + Q_s
    mfma_gemm_kernel<2><<<dim3(8 * mchunk * NB3, 1), 256, 0, stream>>>(
        h2, h2, Bt3, Qh, N_NODES, NQ, NQ, HID, HID, HID, NB3, MB, mchunk);
    agg3_kernel<<<N_NODES / 2, 256, 0, stream>>>(Qh, offs, csr_src, csr_w, out);
}